// Round 1
// baseline (896.746 us; speedup 1.0000x reference)
//
#include <hip/hip_runtime.h>
#include <math.h>

// ---------------------------------------------------------------------------
// Problem: out = x + W2·gelu_fftlow(W1·x + b1) + b2   (skip connect)
// x: [16,64,64,768] f32;  W1: [192,768]; b1: [192]; W2: [768,192]; b2: [768]
// fft_low == per-(b,d) 64x64 plane circular low-pass:
//   y = R P R^T - I P I^T,  R/I = Re/Im of circulant Dirichlet kernel
//   g(d) = (1/64) sum_{k=-16}^{15} e^{2*pi*i*k*d/64}
// Intermediates xs1, xs2 stored bf16 in d_ws, layout [(b*192+d)*4096 + h*64+w]
// ---------------------------------------------------------------------------

typedef unsigned short u16;

__device__ __forceinline__ float bf2f(u16 u) {
    union { unsigned int i; float f; } v; v.i = ((unsigned int)u) << 16; return v.f;
}
__device__ __forceinline__ u16 f2bf(float f) {
    union { unsigned int i; float f; } v; v.f = f;
    unsigned int r = v.i + 0x7FFFu + ((v.i >> 16) & 1u);   // RNE
    return (u16)(r >> 16);
}

#define BM 64
#define BN 64
#define BK 16

// ---------------- GEMM1: xs1[m,d] = gelu( sum_k X[m,k]*W1[d,k] + b1[d] ) ----
// store xs1 in [b][d][m'] layout (m' = m & 4095 = h*64+w), bf16
__global__ __launch_bounds__(256) void gemm1_gelu(
    const float* __restrict__ X, const float* __restrict__ W1,
    const float* __restrict__ b1, u16* __restrict__ XS1)
{
    __shared__ float As[BK][BM + 4];
    __shared__ float Bs[BK][BN + 4];
    const int m0 = blockIdx.x * BM;
    const int n0 = blockIdx.y * BN;
    const int t  = threadIdx.x;
    const int tm = t & 15;       // m-dir, lane-fast
    const int tn = t >> 4;       // d-dir

    float acc[4][4] = {};
    for (int k0 = 0; k0 < 768; k0 += BK) {
        #pragma unroll
        for (int l = 0; l < 4; ++l) {
            int e = t + 256 * l;
            int r = e >> 4, kk = e & 15;
            As[kk][r] = X [(size_t)(m0 + r) * 768 + k0 + kk];
            Bs[kk][r] = W1[(size_t)(n0 + r) * 768 + k0 + kk];
        }
        __syncthreads();
        #pragma unroll
        for (int kk = 0; kk < BK; ++kk) {
            const float4 av = *(const float4*)&As[kk][tm * 4];
            const float4 bv = *(const float4*)&Bs[kk][tn * 4];
            const float a[4] = {av.x, av.y, av.z, av.w};
            const float b[4] = {bv.x, bv.y, bv.z, bv.w};
            #pragma unroll
            for (int i = 0; i < 4; ++i)
                #pragma unroll
                for (int j = 0; j < 4; ++j)
                    acc[i][j] += a[i] * b[j];
        }
        __syncthreads();
    }
    // epilogue: bias + exact gelu, store bf16 to [b][d][m'] layout
    const int bb  = m0 >> 12;
    const int mp0 = (m0 & 4095) + tm * 4;
    #pragma unroll
    for (int j = 0; j < 4; ++j) {
        const int d = n0 + tn * 4 + j;
        const float bias = b1[d];
        u16* dst = XS1 + ((size_t)(bb * 192 + d) << 12) + mp0;
        ushort4 pk;
        float v;
        v = acc[0][j] + bias; v = 0.5f * v * (1.0f + erff(v * 0.70710678118f)); pk.x = f2bf(v);
        v = acc[1][j] + bias; v = 0.5f * v * (1.0f + erff(v * 0.70710678118f)); pk.y = f2bf(v);
        v = acc[2][j] + bias; v = 0.5f * v * (1.0f + erff(v * 0.70710678118f)); pk.z = f2bf(v);
        v = acc[3][j] + bias; v = 0.5f * v * (1.0f + erff(v * 0.70710678118f)); pk.w = f2bf(v);
        *(ushort4*)dst = pk;
    }
}

// ---------------- FFT low-pass filter per plane ----------------------------
// y = R P R^T - I P I^T computed as:
//   stage1: A[w][n2] = sum_h P[w][h]*gR[(h-n2)&63];  B likewise with gI
//   stage2: y[n1][n2] = sum_w gR[(n1-w)&63]*A[w][n2] + gI[(n1-w)&63]*B[w][n2]
// then xs2 = |y|
__global__ __launch_bounds__(256) void fftfilt(
    const u16* __restrict__ XS1, u16* __restrict__ XS2)
{
    __shared__ float P [4096];
    __shared__ float Ab[4096];
    __shared__ float Bb[4096];
    __shared__ float gR[64], gI[64];

    const int t = threadIdx.x;
    const size_t base = (size_t)blockIdx.x << 12;
    const u16* src = XS1 + base;
    u16*       dst = XS2 + base;

    if (t < 64) {   // Dirichlet kernel tables, exact summation
        float rr = 0.f, ii = 0.f;
        for (int k = -16; k < 16; ++k) {
            int md = ((k * t) % 64 + 64) % 64;
            float ang = (float)md * 0.09817477042468103f;   // pi/32
            rr += cosf(ang);
            ii += sinf(ang);
        }
        gR[t] = rr * 0.015625f;
        gI[t] = ii * 0.015625f;
    }
    for (int e = t; e < 4096; e += 256) P[e] = bf2f(src[e]);
    __syncthreads();

    // stage 1 (contract over h): wave has fixed w, n2 = lane
    for (int e = t; e < 4096; e += 256) {
        const int w = e >> 6, n2 = e & 63;
        const float* Pr = &P[w << 6];
        float sa = 0.f, sb = 0.f;
        #pragma unroll 16
        for (int h = 0; h < 64; ++h) {
            const float p = Pr[h];
            const int dd = (h - n2) & 63;
            sa += p * gR[dd];
            sb += p * gI[dd];
        }
        Ab[e] = sa; Bb[e] = sb;
    }
    __syncthreads();

    // stage 2 (contract over w)
    for (int e = t; e < 4096; e += 256) {
        const int n1 = e >> 6, n2 = e & 63;
        float s = 0.f;
        #pragma unroll 16
        for (int w = 0; w < 64; ++w) {
            const int dd = (n1 - w) & 63;
            s += gR[dd] * Ab[(w << 6) + n2] + gI[dd] * Bb[(w << 6) + n2];
        }
        dst[e] = f2bf(fabsf(s));
    }
}

// ---------------- GEMM2: out[m,c] = X[m,c] + b2[c] + sum_d xs2[m,d]*W2[c,d] -
__global__ __launch_bounds__(256) void gemm2_add(
    const u16* __restrict__ XS2, const float* __restrict__ W2,
    const float* __restrict__ b2, const float* __restrict__ X,
    float* __restrict__ OUT)
{
    __shared__ float As[BK][BM + 4];   // [k][m]
    __shared__ float Bs[BK][BN + 4];   // [k][c]
    const int m0 = blockIdx.x * BM;
    const int n0 = blockIdx.y * BN;
    const int t  = threadIdx.x;
    const int tn = t & 15;       // c-dir, lane-fast (coalesced f32 output)
    const int tm = t >> 4;       // m-dir
    const int bb  = m0 >> 12;
    const int mp0 = m0 & 4095;

    float acc[4][4] = {};
    for (int k0 = 0; k0 < 192; k0 += BK) {
        #pragma unroll
        for (int l = 0; l < 4; ++l) {
            int e = t + 256 * l;
            int kk = e >> 6, r = e & 63;   // A tile: 16 k x 64 m, coalesced in m'
            As[kk][r] = bf2f(XS2[((size_t)(bb * 192 + k0 + kk) << 12) + mp0 + r]);
        }
        #pragma unroll
        for (int l = 0; l < 4; ++l) {
            int e = t + 256 * l;
            int cc = e >> 4, kk = e & 15;  // B tile: 64 c x 16 k
            Bs[kk][cc] = W2[(size_t)(n0 + cc) * 192 + k0 + kk];
        }
        __syncthreads();
        #pragma unroll
        for (int kk = 0; kk < BK; ++kk) {
            const float4 av = *(const float4*)&As[kk][tm * 4];
            const float4 bv = *(const float4*)&Bs[kk][tn * 4];
            const float a[4] = {av.x, av.y, av.z, av.w};
            const float b[4] = {bv.x, bv.y, bv.z, bv.w};
            #pragma unroll
            for (int i = 0; i < 4; ++i)
                #pragma unroll
                for (int j = 0; j < 4; ++j)
                    acc[i][j] += a[i] * b[j];
        }
        __syncthreads();
    }
    // epilogue: + b2 + skip, coalesced float4 stores
    const int c0 = n0 + tn * 4;
    const float4 bv = *(const float4*)&b2[c0];
    #pragma unroll
    for (int i = 0; i < 4; ++i) {
        const int m = m0 + tm * 4 + i;
        const float4 xv = *(const float4*)&X[(size_t)m * 768 + c0];
        float4 o;
        o.x = acc[i][0] + bv.x + xv.x;
        o.y = acc[i][1] + bv.y + xv.y;
        o.z = acc[i][2] + bv.z + xv.z;
        o.w = acc[i][3] + bv.w + xv.w;
        *(float4*)&OUT[(size_t)m * 768 + c0] = o;
    }
}

// ---------------------------------------------------------------------------
extern "C" void kernel_launch(void* const* d_in, const int* in_sizes, int n_in,
                              void* d_out, int out_size, void* d_ws, size_t ws_size,
                              hipStream_t stream) {
    (void)in_sizes; (void)n_in; (void)out_size; (void)ws_size;
    const float* X  = (const float*)d_in[0];
    const float* W1 = (const float*)d_in[1];
    const float* b1 = (const float*)d_in[2];
    const float* W2 = (const float*)d_in[3];
    const float* b2 = (const float*)d_in[4];
    float* OUT = (float*)d_out;

    // workspace: xs1 (25.2 MB bf16) | xs2 (25.2 MB bf16)
    u16* xs1 = (u16*)d_ws;
    u16* xs2 = xs1 + (size_t)16 * 192 * 4096;

    gemm1_gelu<<<dim3(1024, 3),  256, 0, stream>>>(X, W1, b1, xs1);
    fftfilt   <<<dim3(3072),     256, 0, stream>>>(xs1, xs2);
    gemm2_add <<<dim3(1024, 12), 256, 0, stream>>>(xs2, W2, b2, X, OUT);
}

// Round 2
// 582.953 us; speedup vs baseline: 1.5383x; 1.5383x over previous
//
#include <hip/hip_runtime.h>
#include <math.h>

// ---------------------------------------------------------------------------
// out = x + W2·gelu_fftlow(W1·x + b1) + b2
// fft_low per 64x64 plane:  Y = R P R + I P I   (R=Re circulant, I=Im)
//   I = -(1/64)(s c^T - c s^T)  (rank 2; only k=-16 mode has imag part)
//   => Y = R (P R) + (1/4096) * rank-4 correction from P's c/s moments
// Filter done with bf16 MFMA 16x16x32; GEMMs unchanged from round 0.
// ---------------------------------------------------------------------------

typedef unsigned short u16;
typedef __attribute__((ext_vector_type(8))) short bf16x8;
typedef __attribute__((ext_vector_type(4))) float f32x4;

__device__ __forceinline__ float bf2f(u16 u) {
    union { unsigned int i; float f; } v; v.i = ((unsigned int)u) << 16; return v.f;
}
__device__ __forceinline__ u16 f2bf(float f) {
    union { unsigned int i; float f; } v; v.f = f;
    unsigned int r = v.i + 0x7FFFu + ((v.i >> 16) & 1u);   // RNE
    return (u16)(r >> 16);
}

// XOR swizzle for row-major [64][64] bf16 LDS tiles (128B rows):
// spreads the same 16B column-chunk of 8 consecutive rows over 8 bank groups.
__device__ __forceinline__ int swzb(int row, int byteInRow) {
    return (row << 7) + (byteInRow ^ ((row & 7) << 4));
}
__device__ __forceinline__ int swzi(int row, int col) {   // -> u16 index
    return swzb(row, col << 1) >> 1;
}

#define BM 64
#define BN 64
#define BK 16
#define PI_32 0.09817477042468103f

// ---------------- GEMM1 (unchanged): xs1 = gelu(X·W1^T + b1), [b][d][m'] ----
__global__ __launch_bounds__(256) void gemm1_gelu(
    const float* __restrict__ X, const float* __restrict__ W1,
    const float* __restrict__ b1, u16* __restrict__ XS1)
{
    __shared__ float As[BK][BM + 4];
    __shared__ float Bs[BK][BN + 4];
    const int m0 = blockIdx.x * BM;
    const int n0 = blockIdx.y * BN;
    const int t  = threadIdx.x;
    const int tm = t & 15;
    const int tn = t >> 4;

    float acc[4][4] = {};
    for (int k0 = 0; k0 < 768; k0 += BK) {
        #pragma unroll
        for (int l = 0; l < 4; ++l) {
            int e = t + 256 * l;
            int r = e >> 4, kk = e & 15;
            As[kk][r] = X [(size_t)(m0 + r) * 768 + k0 + kk];
            Bs[kk][r] = W1[(size_t)(n0 + r) * 768 + k0 + kk];
        }
        __syncthreads();
        #pragma unroll
        for (int kk = 0; kk < BK; ++kk) {
            const float4 av = *(const float4*)&As[kk][tm * 4];
            const float4 bv = *(const float4*)&Bs[kk][tn * 4];
            const float a[4] = {av.x, av.y, av.z, av.w};
            const float b[4] = {bv.x, bv.y, bv.z, bv.w};
            #pragma unroll
            for (int i = 0; i < 4; ++i)
                #pragma unroll
                for (int j = 0; j < 4; ++j)
                    acc[i][j] += a[i] * b[j];
        }
        __syncthreads();
    }
    const int bb  = m0 >> 12;
    const int mp0 = (m0 & 4095) + tm * 4;
    #pragma unroll
    for (int j = 0; j < 4; ++j) {
        const int d = n0 + tn * 4 + j;
        const float bias = b1[d];
        u16* dst = XS1 + ((size_t)(bb * 192 + d) << 12) + mp0;
        ushort4 pk;
        float v;
        v = acc[0][j] + bias; v = 0.5f * v * (1.0f + erff(v * 0.70710678118f)); pk.x = f2bf(v);
        v = acc[1][j] + bias; v = 0.5f * v * (1.0f + erff(v * 0.70710678118f)); pk.y = f2bf(v);
        v = acc[2][j] + bias; v = 0.5f * v * (1.0f + erff(v * 0.70710678118f)); pk.z = f2bf(v);
        v = acc[3][j] + bias; v = 0.5f * v * (1.0f + erff(v * 0.70710678118f)); pk.w = f2bf(v);
        *(ushort4*)dst = pk;
    }
}

// ---------------- FFT low-pass, MFMA version ------------------------------
// block = 256 threads = 4 waves; wave w handles plane blockIdx*4 + w.
// LDS: Rb (shared 8KB) + per-wave P (8KB) + T1t (8KB)  => ~72.3 KB/block.
__global__ __launch_bounds__(256) void fftfilt_mfma(
    const u16* __restrict__ XS1, u16* __restrict__ XS2)
{
    __shared__ u16  Rb[64 * 64];       // R table, swizzled row-major (symmetric)
    __shared__ float gRf[64];
    __shared__ u16  Pb [4][64 * 64];   // plane, later reused for |Y|
    __shared__ u16  T1t[4][64 * 64];   // (P·R)^T, swizzled

    const int t  = threadIdx.x;
    const int wv = t >> 6;
    const int l  = t & 63;

    // Dirichlet real kernel gR
    if (t < 64) {
        float rr = 0.f;
        for (int k = -16; k < 16; ++k) {
            int md = ((k * t) % 64 + 64) % 64;
            rr += cosf((float)md * PI_32);
        }
        gRf[t] = rr * 0.015625f;
    }
    __syncthreads();
    for (int e = t; e < 4096; e += 256) {
        int i = e >> 6, j = e & 63;
        Rb[swzi(i, j)] = f2bf(gRf[(i - j) & 63]);
    }
    __syncthreads();

    const int plane = (blockIdx.x << 2) + wv;
    const u16* src = XS1 + ((size_t)plane << 12);
    u16*       dst = XS2 + ((size_t)plane << 12);
    u16* P  = &Pb [wv][0];
    u16* Tt = &T1t[wv][0];

    // ---- load plane into LDS (swizzled), coalesced 16B per lane ----
    #pragma unroll
    for (int it = 0; it < 8; ++it) {
        const int e0 = it * 512 + l * 8;
        bf16x8 v = *(const bf16x8*)&src[e0];
        *(bf16x8*)&P[swzi(e0 >> 6, e0 & 63)] = v;
    }

    // ---- rank-4 correction moments: vc[a]=P[a]·c, vs[a]=P[a]·s ----
    float vc = 0.f, vs = 0.f;
    #pragma unroll
    for (int jc = 0; jc < 8; ++jc) {
        bf16x8 v = *(bf16x8*)&P[swzi(l, jc * 8)];
        vc += bf2f((u16)v[0]) - bf2f((u16)v[2]) + bf2f((u16)v[4]) - bf2f((u16)v[6]);
        vs += bf2f((u16)v[1]) - bf2f((u16)v[3]) + bf2f((u16)v[5]) - bf2f((u16)v[7]);
    }
    const float cl = (l & 1) ? 0.f : ((l & 2) ? -1.f : 1.f);
    const float sl = (l & 1) ? ((l & 2) ? -1.f : 1.f) : 0.f;
    float p1 = cl * vc, p2 = cl * vs, p3 = sl * vc, p4 = sl * vs;
    #pragma unroll
    for (int off = 32; off; off >>= 1) {
        p1 += __shfl_xor(p1, off);
        p2 += __shfl_xor(p2, off);
        p3 += __shfl_xor(p3, off);
        p4 += __shfl_xor(p4, off);
    }

    const int fr = l & 15;         // fragment row/col index
    const int fk = (l >> 4) << 4;  // fragment k byte base (16B chunk)

    // ---- stage 1: T1 = P·R, stored transposed ----
    #pragma unroll
    for (int ti = 0; ti < 4; ++ti)
        #pragma unroll
        for (int tj = 0; tj < 4; ++tj) {
            f32x4 acc = {0.f, 0.f, 0.f, 0.f};
            #pragma unroll
            for (int kk = 0; kk < 2; ++kk) {
                bf16x8 a = *(bf16x8*)&P [swzb(ti * 16 + fr, (kk << 6) + fk) >> 1];
                bf16x8 b = *(bf16x8*)&Rb[swzb(tj * 16 + fr, (kk << 6) + fk) >> 1];
                acc = __builtin_amdgcn_mfma_f32_16x16x32_bf16(a, b, acc, 0, 0, 0);
            }
            const int n2 = tj * 16 + fr;
            const int w0 = ti * 16 + ((l >> 4) << 2);
            uint2 pk;
            pk.x = (unsigned)f2bf(acc[0]) | ((unsigned)f2bf(acc[1]) << 16);
            pk.y = (unsigned)f2bf(acc[2]) | ((unsigned)f2bf(acc[3]) << 16);
            *(uint2*)&Tt[swzb(n2, w0 << 1) >> 1] = pk;
        }

    // ---- stage 2: Y = R·T1 + corr; |Y| -> P buffer (reused) ----
    const float inv4096 = 1.f / 4096.f;
    #pragma unroll
    for (int ti = 0; ti < 4; ++ti)
        #pragma unroll
        for (int tj = 0; tj < 4; ++tj) {
            f32x4 acc = {0.f, 0.f, 0.f, 0.f};
            #pragma unroll
            for (int kk = 0; kk < 2; ++kk) {
                bf16x8 a = *(bf16x8*)&Rb[swzb(ti * 16 + fr, (kk << 6) + fk) >> 1];
                bf16x8 b = *(bf16x8*)&Tt[swzb(tj * 16 + fr, (kk << 6) + fk) >> 1];
                acc = __builtin_amdgcn_mfma_f32_16x16x32_bf16(a, b, acc, 0, 0, 0);
            }
            const int a0   = ti * 16 + ((l >> 4) << 2);
            const int bcol = tj * 16 + fr;
            const float cb = (bcol & 1) ? 0.f : ((bcol & 2) ? -1.f : 1.f);
            const float sb = (bcol & 1) ? ((bcol & 2) ? -1.f : 1.f) : 0.f;
            #pragma unroll
            for (int r = 0; r < 4; ++r) {
                const int aa = a0 + r;
                const float ca = (aa & 1) ? 0.f : ((aa & 2) ? -1.f : 1.f);
                const float sa = (aa & 1) ? ((aa & 2) ? -1.f : 1.f) : 0.f;
                const float corr = inv4096 *
                    (p2 * sa * cb - p1 * sa * sb - p4 * ca * cb + p3 * ca * sb);
                P[swzi(aa, bcol)] = f2bf(fabsf(acc[r] + corr));
            }
        }

    // ---- coalesced copy-out ----
    #pragma unroll
    for (int it = 0; it < 8; ++it) {
        const int e0 = it * 512 + l * 8;
        bf16x8 v = *(bf16x8*)&P[swzi(e0 >> 6, e0 & 63)];
        *(bf16x8*)&dst[e0] = v;
    }
}

// ---------------- GEMM2 (unchanged): out = X + xs2·W2^T + b2 ---------------
__global__ __launch_bounds__(256) void gemm2_add(
    const u16* __restrict__ XS2, const float* __restrict__ W2,
    const float* __restrict__ b2, const float* __restrict__ X,
    float* __restrict__ OUT)
{
    __shared__ float As[BK][BM + 4];
    __shared__ float Bs[BK][BN + 4];
    const int m0 = blockIdx.x * BM;
    const int n0 = blockIdx.y * BN;
    const int t  = threadIdx.x;
    const int tn = t & 15;
    const int tm = t >> 4;
    const int bb  = m0 >> 12;
    const int mp0 = m0 & 4095;

    float acc[4][4] = {};
    for (int k0 = 0; k0 < 192; k0 += BK) {
        #pragma unroll
        for (int l = 0; l < 4; ++l) {
            int e = t + 256 * l;
            int kk = e >> 6, r = e & 63;
            As[kk][r] = bf2f(XS2[((size_t)(bb * 192 + k0 + kk) << 12) + mp0 + r]);
        }
        #pragma unroll
        for (int l = 0; l < 4; ++l) {
            int e = t + 256 * l;
            int cc = e >> 4, kk = e & 15;
            Bs[kk][cc] = W2[(size_t)(n0 + cc) * 192 + k0 + kk];
        }
        __syncthreads();
        #pragma unroll
        for (int kk = 0; kk < BK; ++kk) {
            const float4 av = *(const float4*)&As[kk][tm * 4];
            const float4 bv = *(const float4*)&Bs[kk][tn * 4];
            const float a[4] = {av.x, av.y, av.z, av.w};
            const float b[4] = {bv.x, bv.y, bv.z, bv.w};
            #pragma unroll
            for (int i = 0; i < 4; ++i)
                #pragma unroll
                for (int j = 0; j < 4; ++j)
                    acc[i][j] += a[i] * b[j];
        }
        __syncthreads();
    }
    const int c0 = n0 + tn * 4;
    const float4 bv = *(const float4*)&b2[c0];
    #pragma unroll
    for (int i = 0; i < 4; ++i) {
        const int m = m0 + tm * 4 + i;
        const float4 xv = *(const float4*)&X[(size_t)m * 768 + c0];
        float4 o;
        o.x = acc[i][0] + bv.x + xv.x;
        o.y = acc[i][1] + bv.y + xv.y;
        o.z = acc[i][2] + bv.z + xv.z;
        o.w = acc[i][3] + bv.w + xv.w;
        *(float4*)&OUT[(size_t)m * 768 + c0] = o;
    }
}

// ---------------------------------------------------------------------------
extern "C" void kernel_launch(void* const* d_in, const int* in_sizes, int n_in,
                              void* d_out, int out_size, void* d_ws, size_t ws_size,
                              hipStream_t stream) {
    (void)in_sizes; (void)n_in; (void)out_size; (void)ws_size;
    const float* X  = (const float*)d_in[0];
    const float* W1 = (const float*)d_in[1];
    const float* b1 = (const float*)d_in[2];
    const float* W2 = (const float*)d_in[3];
    const float* b2 = (const float*)d_in[4];
    float* OUT = (float*)d_out;

    u16* xs1 = (u16*)d_ws;
    u16* xs2 = xs1 + (size_t)16 * 192 * 4096;

    gemm1_gelu  <<<dim3(1024, 3),  256, 0, stream>>>(X, W1, b1, xs1);
    fftfilt_mfma<<<dim3(768),      256, 0, stream>>>(xs1, xs2);
    gemm2_add   <<<dim3(1024, 12), 256, 0, stream>>>(xs2, W2, b2, X, OUT);
}

// Round 3
// 194.692 us; speedup vs baseline: 4.6060x; 2.9942x over previous
//
#include <hip/hip_runtime.h>
#include <math.h>

// ---------------------------------------------------------------------------
// out = x + W2·gelu_fftlow(W1·x + b1) + b2
//  gemm1_mfma:  xs1[b][d][m'] = gelu(X·W1^T + b1)          (bf16 MFMA)
//  fftfilt_mfma: per-plane circular low-pass (verified, unchanged)
//  transpose_dm: xs2 [b][d][m'] -> xs2t [b][m'][d]
//  gemm2_mfma:  OUT = X + xs2t·W2^T + b2                   (bf16 MFMA, A in regs)
// ws: region0 (24MB) = xs1 then xs2t ; region1 (24MB) = xs2
// ---------------------------------------------------------------------------

typedef unsigned short u16;
typedef __attribute__((ext_vector_type(8))) short bf16x8;
typedef __attribute__((ext_vector_type(4))) float f32x4;

__device__ __forceinline__ float bf2f(u16 u) {
    union { unsigned int i; float f; } v; v.i = ((unsigned int)u) << 16; return v.f;
}
__device__ __forceinline__ u16 f2bf(float f) {
    union { unsigned int i; float f; } v; v.f = f;
    unsigned int r = v.i + 0x7FFFu + ((v.i >> 16) & 1u);   // RNE
    return (u16)(r >> 16);
}

// generic row XOR-swizzle, u16 units; rowU16 multiple of 64 (128B)
__device__ __forceinline__ int swz(int row, int rowU16, int colU16) {
    int cb = colU16 & ~7;          // 16B chunk base (8 u16)
    int ci = colU16 & 7;
    return row * rowU16 + (cb ^ ((row & 7) << 3)) + ci;
}

// fftfilt's own swizzle (verified round 1/2)
__device__ __forceinline__ int swzb(int row, int byteInRow) {
    return (row << 7) + (byteInRow ^ ((row & 7) << 4));
}
__device__ __forceinline__ int swzi(int row, int col) {
    return swzb(row, col << 1) >> 1;
}

#define PI_32 0.09817477042468103f

// ============================ GEMM1 (MFMA) =================================
// grid 512, 512 threads (8 waves: 2m x 4n), BM=128, BN=192, BK=64
__global__ __launch_bounds__(512, 4) void gemm1_mfma(
    const float* __restrict__ X, const float* __restrict__ W1,
    const float* __restrict__ b1, u16* __restrict__ XS1)
{
    __shared__ u16 As[128 * 64];   // [m][k] swizzled, rows 64 u16
    __shared__ u16 Bs[192 * 64];   // [d][k] swizzled
    const int t  = threadIdx.x, wv = t >> 6, l = t & 63;
    const int m0 = blockIdx.x * 128;
    const int bb = m0 >> 12, mp0 = m0 & 4095;
    const int fr  = l & 15;
    const int fko = (l >> 4) << 3;           // k offset (u16) within 32-chunk
    const int wm = (wv & 1) * 64, wn = (wv >> 1) * 48;

    f32x4 acc[4][3];
    #pragma unroll
    for (int i = 0; i < 4; ++i)
        #pragma unroll
        for (int j = 0; j < 3; ++j)
            acc[i][j] = (f32x4){0.f, 0.f, 0.f, 0.f};

    for (int k0 = 0; k0 < 768; k0 += 64) {
        // ---- stage A: 128x64 f32 -> bf16 (16 floats/thread) ----
        {
            const int row = t >> 2, c4 = (t & 3) << 4;
            const float* s = &X[(size_t)(m0 + row) * 768 + k0 + c4];
            float4 f0 = *(const float4*)(s);
            float4 f1 = *(const float4*)(s + 4);
            float4 f2 = *(const float4*)(s + 8);
            float4 f3 = *(const float4*)(s + 12);
            bf16x8 p0, p1;
            p0[0]=f2bf(f0.x); p0[1]=f2bf(f0.y); p0[2]=f2bf(f0.z); p0[3]=f2bf(f0.w);
            p0[4]=f2bf(f1.x); p0[5]=f2bf(f1.y); p0[6]=f2bf(f1.z); p0[7]=f2bf(f1.w);
            p1[0]=f2bf(f2.x); p1[1]=f2bf(f2.y); p1[2]=f2bf(f2.z); p1[3]=f2bf(f2.w);
            p1[4]=f2bf(f3.x); p1[5]=f2bf(f3.y); p1[6]=f2bf(f3.z); p1[7]=f2bf(f3.w);
            *(bf16x8*)&As[swz(row, 64, c4)]     = p0;
            *(bf16x8*)&As[swz(row, 64, c4 + 8)] = p1;
        }
        // ---- stage B: 192x64 f32 -> bf16 (6 float4/thread) ----
        #pragma unroll
        for (int i = 0; i < 6; ++i) {
            int e = t + i * 512;              // 0..3071
            int row = e >> 4, fc = e & 15;
            float4 f = *(const float4*)&W1[(size_t)row * 768 + k0 + fc * 4];
            short4 p;
            p.x = (short)f2bf(f.x); p.y = (short)f2bf(f.y);
            p.z = (short)f2bf(f.z); p.w = (short)f2bf(f.w);
            *(short4*)&Bs[swz(row, 64, fc * 4)] = p;
        }
        __syncthreads();
        #pragma unroll
        for (int kk = 0; kk < 2; ++kk) {
            bf16x8 b0 = *(bf16x8*)&Bs[swz(wn +  0 + fr, 64, kk * 32 + fko)];
            bf16x8 b1v= *(bf16x8*)&Bs[swz(wn + 16 + fr, 64, kk * 32 + fko)];
            bf16x8 b2v= *(bf16x8*)&Bs[swz(wn + 32 + fr, 64, kk * 32 + fko)];
            #pragma unroll
            for (int mi = 0; mi < 4; ++mi) {
                bf16x8 a = *(bf16x8*)&As[swz(wm + mi * 16 + fr, 64, kk * 32 + fko)];
                acc[mi][0] = __builtin_amdgcn_mfma_f32_16x16x32_bf16(a, b0,  acc[mi][0], 0, 0, 0);
                acc[mi][1] = __builtin_amdgcn_mfma_f32_16x16x32_bf16(a, b1v, acc[mi][1], 0, 0, 0);
                acc[mi][2] = __builtin_amdgcn_mfma_f32_16x16x32_bf16(a, b2v, acc[mi][2], 0, 0, 0);
            }
        }
        __syncthreads();
    }

    // ---- epilogue: bias + exact gelu -> xs1 [d][m'] ----
    const int mr = mp0 + wm + (l >> 4) * 4;
    #pragma unroll
    for (int nj = 0; nj < 3; ++nj) {
        const int d = wn + nj * 16 + fr;
        const float bias = b1[d];
        u16* dst = XS1 + ((size_t)(bb * 192 + d) << 12);
        #pragma unroll
        for (int mi = 0; mi < 4; ++mi) {
            ushort4 pk; float v;
            v = acc[mi][nj][0] + bias; v = 0.5f*v*(1.f+erff(v*0.70710678118f)); pk.x = f2bf(v);
            v = acc[mi][nj][1] + bias; v = 0.5f*v*(1.f+erff(v*0.70710678118f)); pk.y = f2bf(v);
            v = acc[mi][nj][2] + bias; v = 0.5f*v*(1.f+erff(v*0.70710678118f)); pk.z = f2bf(v);
            v = acc[mi][nj][3] + bias; v = 0.5f*v*(1.f+erff(v*0.70710678118f)); pk.w = f2bf(v);
            *(ushort4*)&dst[mr + mi * 16] = pk;
        }
    }
}

// ===================== FFT low-pass (verified, unchanged) ==================
__global__ __launch_bounds__(256) void fftfilt_mfma(
    const u16* __restrict__ XS1, u16* __restrict__ XS2)
{
    __shared__ u16  Rb[64 * 64];
    __shared__ float gRf[64];
    __shared__ u16  Pb [4][64 * 64];
    __shared__ u16  T1t[4][64 * 64];

    const int t  = threadIdx.x;
    const int wv = t >> 6;
    const int l  = t & 63;

    if (t < 64) {
        float rr = 0.f;
        for (int k = -16; k < 16; ++k) {
            int md = ((k * t) % 64 + 64) % 64;
            rr += cosf((float)md * PI_32);
        }
        gRf[t] = rr * 0.015625f;
    }
    __syncthreads();
    for (int e = t; e < 4096; e += 256) {
        int i = e >> 6, j = e & 63;
        Rb[swzi(i, j)] = f2bf(gRf[(i - j) & 63]);
    }
    __syncthreads();

    const int plane = (blockIdx.x << 2) + wv;
    const u16* src = XS1 + ((size_t)plane << 12);
    u16*       dst = XS2 + ((size_t)plane << 12);
    u16* P  = &Pb [wv][0];
    u16* Tt = &T1t[wv][0];

    #pragma unroll
    for (int it = 0; it < 8; ++it) {
        const int e0 = it * 512 + l * 8;
        bf16x8 v = *(const bf16x8*)&src[e0];
        *(bf16x8*)&P[swzi(e0 >> 6, e0 & 63)] = v;
    }

    float vc = 0.f, vs = 0.f;
    #pragma unroll
    for (int jc = 0; jc < 8; ++jc) {
        bf16x8 v = *(bf16x8*)&P[swzi(l, jc * 8)];
        vc += bf2f((u16)v[0]) - bf2f((u16)v[2]) + bf2f((u16)v[4]) - bf2f((u16)v[6]);
        vs += bf2f((u16)v[1]) - bf2f((u16)v[3]) + bf2f((u16)v[5]) - bf2f((u16)v[7]);
    }
    const float cl = (l & 1) ? 0.f : ((l & 2) ? -1.f : 1.f);
    const float sl = (l & 1) ? ((l & 2) ? -1.f : 1.f) : 0.f;
    float p1 = cl * vc, p2 = cl * vs, p3 = sl * vc, p4 = sl * vs;
    #pragma unroll
    for (int off = 32; off; off >>= 1) {
        p1 += __shfl_xor(p1, off);
        p2 += __shfl_xor(p2, off);
        p3 += __shfl_xor(p3, off);
        p4 += __shfl_xor(p4, off);
    }

    const int fr = l & 15;
    const int fk = (l >> 4) << 4;

    #pragma unroll
    for (int ti = 0; ti < 4; ++ti)
        #pragma unroll
        for (int tj = 0; tj < 4; ++tj) {
            f32x4 acc = {0.f, 0.f, 0.f, 0.f};
            #pragma unroll
            for (int kk = 0; kk < 2; ++kk) {
                bf16x8 a = *(bf16x8*)&P [swzb(ti * 16 + fr, (kk << 6) + fk) >> 1];
                bf16x8 b = *(bf16x8*)&Rb[swzb(tj * 16 + fr, (kk << 6) + fk) >> 1];
                acc = __builtin_amdgcn_mfma_f32_16x16x32_bf16(a, b, acc, 0, 0, 0);
            }
            const int n2 = tj * 16 + fr;
            const int w0 = ti * 16 + ((l >> 4) << 2);
            uint2 pk;
            pk.x = (unsigned)f2bf(acc[0]) | ((unsigned)f2bf(acc[1]) << 16);
            pk.y = (unsigned)f2bf(acc[2]) | ((unsigned)f2bf(acc[3]) << 16);
            *(uint2*)&Tt[swzb(n2, w0 << 1) >> 1] = pk;
        }

    const float inv4096 = 1.f / 4096.f;
    #pragma unroll
    for (int ti = 0; ti < 4; ++ti)
        #pragma unroll
        for (int tj = 0; tj < 4; ++tj) {
            f32x4 acc = {0.f, 0.f, 0.f, 0.f};
            #pragma unroll
            for (int kk = 0; kk < 2; ++kk) {
                bf16x8 a = *(bf16x8*)&Rb[swzb(ti * 16 + fr, (kk << 6) + fk) >> 1];
                bf16x8 b = *(bf16x8*)&Tt[swzb(tj * 16 + fr, (kk << 6) + fk) >> 1];
                acc = __builtin_amdgcn_mfma_f32_16x16x32_bf16(a, b, acc, 0, 0, 0);
            }
            const int a0   = ti * 16 + ((l >> 4) << 2);
            const int bcol = tj * 16 + fr;
            const float cb = (bcol & 1) ? 0.f : ((bcol & 2) ? -1.f : 1.f);
            const float sb = (bcol & 1) ? ((bcol & 2) ? -1.f : 1.f) : 0.f;
            #pragma unroll
            for (int r = 0; r < 4; ++r) {
                const int aa = a0 + r;
                const float ca = (aa & 1) ? 0.f : ((aa & 2) ? -1.f : 1.f);
                const float sa = (aa & 1) ? ((aa & 2) ? -1.f : 1.f) : 0.f;
                const float corr = inv4096 *
                    (p2 * sa * cb - p1 * sa * sb - p4 * ca * cb + p3 * ca * sb);
                P[swzi(aa, bcol)] = f2bf(fabsf(acc[r] + corr));
            }
        }

    #pragma unroll
    for (int it = 0; it < 8; ++it) {
        const int e0 = it * 512 + l * 8;
        bf16x8 v = *(bf16x8*)&P[swzi(e0 >> 6, e0 & 63)];
        *(bf16x8*)&dst[e0] = v;
    }
}

// ===================== transpose: [b][d][m'] -> [b][m'][d] =================
// grid 16*64, 256 threads; block = (b, 64-row m-block)
__global__ __launch_bounds__(256) void transpose_dm(
    const u16* __restrict__ XS2, u16* __restrict__ XT)
{
    __shared__ u16 Lt[64 * 192];
    const int t  = threadIdx.x;
    const int b  = blockIdx.x >> 6;
    const int mb = blockIdx.x & 63;
    const int d0 = t >> 3, mc = t & 7;
    #pragma unroll
    for (int i = 0; i < 6; ++i) {
        const int d = d0 + i * 32;
        bf16x8 v = *(const bf16x8*)&XS2[((size_t)(b * 192 + d) << 12) + mb * 64 + mc * 8];
        #pragma unroll
        for (int j = 0; j < 8; ++j) {
            const int row = mc * 8 + j;
            Lt[row * 192 + (((d >> 3) << 3) ^ (mc << 3)) + (d & 7)] = (u16)v[j];
        }
    }
    __syncthreads();
    const int row = t >> 2;
    u16* dstb = XT + (size_t)((b << 12) + mb * 64 + row) * 192;
    #pragma unroll
    for (int i = 0; i < 6; ++i) {
        const int dc = (t & 3) + i * 4;    // 16B chunk 0..23
        bf16x8 v = *(bf16x8*)&Lt[row * 192 + ((dc * 8) ^ ((row >> 3) << 3))];
        *(bf16x8*)&dstb[dc * 8] = v;
    }
}

// ============================ GEMM2 (MFMA) =================================
// grid 512, 256 threads (4 waves: 2m x 2c); A-slice in regs, loops 12 c-tiles
__global__ __launch_bounds__(256, 2) void gemm2_mfma(
    const u16* __restrict__ XT, const float* __restrict__ W2,
    const float* __restrict__ b2, const float* __restrict__ X,
    float* __restrict__ OUT)
{
    __shared__ u16 Bs[64 * 192];   // [c][d] swizzled, rows 192 u16
    const int t  = threadIdx.x, wv = t >> 6, l = t & 63;
    const int m0 = blockIdx.x * 128;
    const int fr  = l & 15;
    const int fko = (l >> 4) << 3;
    const int wm = (wv & 1) * 64, wc = (wv >> 1) * 32;

    // A fragments straight from global (64B-coalesced per 16-lane group)
    bf16x8 areg[4][6];
    #pragma unroll
    for (int mi = 0; mi < 4; ++mi)
        #pragma unroll
        for (int kk = 0; kk < 6; ++kk)
            areg[mi][kk] = *(const bf16x8*)&XT[(size_t)(m0 + wm + mi * 16 + fr) * 192 + kk * 32 + fko];

    for (int ct = 0; ct < 12; ++ct) {
        const int c0 = ct * 64;
        // stage B: 64x192 f32 -> bf16 (12 float4/thread)
        #pragma unroll
        for (int i = 0; i < 12; ++i) {
            int e = t + i * 256;           // 0..3071
            int row = e / 48, fc = e % 48;
            float4 f = *(const float4*)&W2[(size_t)(c0 + row) * 192 + fc * 4];
            short4 p;
            p.x = (short)f2bf(f.x); p.y = (short)f2bf(f.y);
            p.z = (short)f2bf(f.z); p.w = (short)f2bf(f.w);
            *(short4*)&Bs[swz(row, 192, fc * 4)] = p;
        }
        __syncthreads();

        f32x4 acc[4][2];
        #pragma unroll
        for (int i = 0; i < 4; ++i) {
            acc[i][0] = (f32x4){0.f, 0.f, 0.f, 0.f};
            acc[i][1] = (f32x4){0.f, 0.f, 0.f, 0.f};
        }
        #pragma unroll
        for (int kk = 0; kk < 6; ++kk) {
            bf16x8 bv0 = *(bf16x8*)&Bs[swz(wc +  0 + fr, 192, kk * 32 + fko)];
            bf16x8 bv1 = *(bf16x8*)&Bs[swz(wc + 16 + fr, 192, kk * 32 + fko)];
            #pragma unroll
            for (int mi = 0; mi < 4; ++mi) {
                acc[mi][0] = __builtin_amdgcn_mfma_f32_16x16x32_bf16(areg[mi][kk], bv0, acc[mi][0], 0, 0, 0);
                acc[mi][1] = __builtin_amdgcn_mfma_f32_16x16x32_bf16(areg[mi][kk], bv1, acc[mi][1], 0, 0, 0);
            }
        }
        // epilogue: + b2 + skip
        #pragma unroll
        for (int cj = 0; cj < 2; ++cj) {
            const int c = c0 + wc + cj * 16 + fr;
            const float bias = b2[c];
            #pragma unroll
            for (int mi = 0; mi < 4; ++mi) {
                const int mbase = m0 + wm + mi * 16 + (l >> 4) * 4;
                #pragma unroll
                for (int r = 0; r < 4; ++r) {
                    const size_t off = (size_t)(mbase + r) * 768 + c;
                    OUT[off] = acc[mi][cj][r] + bias + X[off];
                }
            }
        }
        __syncthreads();
    }
}

// ---------------------------------------------------------------------------
extern "C" void kernel_launch(void* const* d_in, const int* in_sizes, int n_in,
                              void* d_out, int out_size, void* d_ws, size_t ws_size,
                              hipStream_t stream) {
    (void)in_sizes; (void)n_in; (void)out_size; (void)ws_size;
    const float* X  = (const float*)d_in[0];
    const float* W1 = (const float*)d_in[1];
    const float* b1 = (const float*)d_in[2];
    const float* W2 = (const float*)d_in[3];
    const float* b2 = (const float*)d_in[4];
    float* OUT = (float*)d_out;

    u16* reg0 = (u16*)d_ws;                              // xs1, later xs2t
    u16* reg1 = reg0 + (size_t)16 * 192 * 4096;          // xs2

    gemm1_mfma  <<<dim3(512),     512, 0, stream>>>(X, W1, b1, reg0);
    fftfilt_mfma<<<dim3(768),     256, 0, stream>>>(reg0, reg1);
    transpose_dm<<<dim3(16 * 64), 256, 0, stream>>>(reg1, reg0);
    gemm2_mfma  <<<dim3(512),     256, 0, stream>>>(reg0, W2, b2, X, OUT);
}